// Round 3
// baseline (45.061 us; speedup 1.0000x reference)
//
#include <hip/hip_runtime.h>

// DIM=2, L=13 (n = 8192 rows), BATCH=2048 cols, Hadamard on wires {0,5,9}
// -> row-index bits {12,7,3}. Real Hadamard => real/imag decouple; harness
// output is the real part (out_size == n*b float32).
// 3-stage +- butterfly over row bits {3,7,12}, scale (1/sqrt(2))^3.
// Each thread: 2 adjacent float4 (32 B) per row-stream -> wave covers 2 KiB
// contiguous per stream, 16 loads in flight.

#define NROWS   8192
#define NCOLS   2048
#define COLS4   (NCOLS / 4)          // 512 float4 per row
#define COLS8   (NCOLS / 8)          // 256 float4-pairs per row
#define NBASE   (NROWS / 8)          // 1024 base rows (bits 12,7,3 clear)
#define SCALE   0.35355339059327373f

// float4-unit strides for the three butterfly bits
#define D3   (8    * COLS4)   // bit 3  -> +8 rows
#define D7   (128  * COLS4)   // bit 7  -> +128 rows
#define D12  (4096 * COLS4)   // bit 12 -> +4096 rows

typedef float f32x4 __attribute__((ext_vector_type(4)));

__global__ __launch_bounds__(256) void had3_kernel(const f32x4* __restrict__ in,
                                                   f32x4* __restrict__ out) {
    int t = blockIdx.x * blockDim.x + threadIdx.x;   // 0 .. NBASE*COLS8-1
    int c    = t & (COLS8 - 1);                      // float4-pair column index
    int base = t >> 8;                               // 0 .. 1023

    // Expand 10 free bits of `base` into row bits {0-2, 4-6, 8-11}
    int r0 = (base & 0x7) | ((base & 0x38) << 1) | ((base & 0x3C0) << 2);
    int idx = r0 * COLS4 + 2 * c;                    // float4 units

    f32x4 v0a = in[idx],            v0b = in[idx + 1];
    f32x4 v1a = in[idx + D3],       v1b = in[idx + D3 + 1];
    f32x4 v2a = in[idx + D7],       v2b = in[idx + D7 + 1];
    f32x4 v3a = in[idx + D7 + D3],  v3b = in[idx + D7 + D3 + 1];
    f32x4 v4a = in[idx + D12],      v4b = in[idx + D12 + 1];
    f32x4 v5a = in[idx + D12 + D3], v5b = in[idx + D12 + D3 + 1];
    f32x4 v6a = in[idx + D12 + D7], v6b = in[idx + D12 + D7 + 1];
    f32x4 v7a = in[idx + D12 + D7 + D3], v7b = in[idx + D12 + D7 + D3 + 1];

    f32x4 s = {SCALE, SCALE, SCALE, SCALE};

    // ---- lane a ----
    {
        f32x4 t0 = v0a + v1a, t1 = v0a - v1a;
        f32x4 t2 = v2a + v3a, t3 = v2a - v3a;
        f32x4 t4 = v4a + v5a, t5 = v4a - v5a;
        f32x4 t6 = v6a + v7a, t7 = v6a - v7a;
        f32x4 u0 = t0 + t2, u2 = t0 - t2;
        f32x4 u1 = t1 + t3, u3 = t1 - t3;
        f32x4 u4 = t4 + t6, u6 = t4 - t6;
        f32x4 u5 = t5 + t7, u7 = t5 - t7;
        out[idx]                 = (u0 + u4) * s;
        out[idx + D3]            = (u1 + u5) * s;
        out[idx + D7]            = (u2 + u6) * s;
        out[idx + D7 + D3]       = (u3 + u7) * s;
        out[idx + D12]           = (u0 - u4) * s;
        out[idx + D12 + D3]      = (u1 - u5) * s;
        out[idx + D12 + D7]      = (u2 - u6) * s;
        out[idx + D12 + D7 + D3] = (u3 - u7) * s;
    }
    // ---- lane b ----
    {
        f32x4 t0 = v0b + v1b, t1 = v0b - v1b;
        f32x4 t2 = v2b + v3b, t3 = v2b - v3b;
        f32x4 t4 = v4b + v5b, t5 = v4b - v5b;
        f32x4 t6 = v6b + v7b, t7 = v6b - v7b;
        f32x4 u0 = t0 + t2, u2 = t0 - t2;
        f32x4 u1 = t1 + t3, u3 = t1 - t3;
        f32x4 u4 = t4 + t6, u6 = t4 - t6;
        f32x4 u5 = t5 + t7, u7 = t5 - t7;
        out[idx + 1]                 = (u0 + u4) * s;
        out[idx + D3 + 1]            = (u1 + u5) * s;
        out[idx + D7 + 1]            = (u2 + u6) * s;
        out[idx + D7 + D3 + 1]       = (u3 + u7) * s;
        out[idx + D12 + 1]           = (u0 - u4) * s;
        out[idx + D12 + D3 + 1]      = (u1 - u5) * s;
        out[idx + D12 + D7 + 1]      = (u2 - u6) * s;
        out[idx + D12 + D7 + D3 + 1] = (u3 - u7) * s;
    }
}

extern "C" void kernel_launch(void* const* d_in, const int* in_sizes, int n_in,
                              void* d_out, int out_size, void* d_ws, size_t ws_size,
                              hipStream_t stream) {
    const float* xr = (const float*)d_in[0];
    const float* xi = (const float*)d_in[1];
    float* out = (float*)d_out;

    const int N = NROWS * NCOLS;               // 16,777,216 elements per part
    const int threads = 256;
    const int total   = NBASE * COLS8;         // 262,144 threads
    const int blocks  = total / threads;       // 1024

    had3_kernel<<<blocks, threads, 0, stream>>>((const f32x4*)xr, (f32x4*)out);

    // Defensive: if the harness wants both parts (concatenated flat),
    // transform the imaginary part into the second half.
    if (out_size >= 2 * N) {
        had3_kernel<<<blocks, threads, 0, stream>>>((const f32x4*)xi,
                                                    (f32x4*)(out + N));
    }
}

// Round 4
// 25.274 us; speedup vs baseline: 1.7829x; 1.7829x over previous
//
#include <hip/hip_runtime.h>

// DIM=2, L=13 (n = 8192 rows), BATCH=2048 cols, Hadamard on wires {0,5,9}
// -> row-index bits {12,7,3}. Real Hadamard => real/imag decouple; harness
// output is the real part (out_size == n*b float32).
// 3-stage +- butterfly over row bits {3,7,12}, scale (1/sqrt(2))^3.
// Each thread: 2 float4 per row-stream at column offsets c and c+256
// (separate column halves) -> every instruction fully coalesced (64 lanes
// x 16 B contiguous), 16 loads in flight per thread.

#define NROWS   8192
#define NCOLS   2048
#define COLS4   (NCOLS / 4)          // 512 float4 per row
#define HCOLS   (COLS4 / 2)          // 256: column-half size in float4
#define NBASE   (NROWS / 8)          // 1024 base rows (bits 12,7,3 clear)
#define SCALE   0.35355339059327373f

// float4-unit strides for the three butterfly bits
#define D3   (8    * COLS4)   // bit 3  -> +8 rows
#define D7   (128  * COLS4)   // bit 7  -> +128 rows
#define D12  (4096 * COLS4)   // bit 12 -> +4096 rows

typedef float f32x4 __attribute__((ext_vector_type(4)));

__global__ __launch_bounds__(256) void had3_kernel(const f32x4* __restrict__ in,
                                                   f32x4* __restrict__ out) {
    int t = blockIdx.x * blockDim.x + threadIdx.x;   // 0 .. NBASE*HCOLS-1
    int c    = t & (HCOLS - 1);                      // float4 column (first half)
    int base = t >> 8;                               // 0 .. 1023

    // Expand 10 free bits of `base` into row bits {0-2, 4-6, 8-11}
    int r0 = (base & 0x7) | ((base & 0x38) << 1) | ((base & 0x3C0) << 2);
    int idx = r0 * COLS4 + c;                        // float4 units

    f32x4 v0a = in[idx],                 v0b = in[idx + HCOLS];
    f32x4 v1a = in[idx + D3],            v1b = in[idx + D3 + HCOLS];
    f32x4 v2a = in[idx + D7],            v2b = in[idx + D7 + HCOLS];
    f32x4 v3a = in[idx + D7 + D3],       v3b = in[idx + D7 + D3 + HCOLS];
    f32x4 v4a = in[idx + D12],           v4b = in[idx + D12 + HCOLS];
    f32x4 v5a = in[idx + D12 + D3],      v5b = in[idx + D12 + D3 + HCOLS];
    f32x4 v6a = in[idx + D12 + D7],      v6b = in[idx + D12 + D7 + HCOLS];
    f32x4 v7a = in[idx + D12 + D7 + D3], v7b = in[idx + D12 + D7 + D3 + HCOLS];

    f32x4 s = {SCALE, SCALE, SCALE, SCALE};

    // ---- column half a ----
    {
        f32x4 t0 = v0a + v1a, t1 = v0a - v1a;
        f32x4 t2 = v2a + v3a, t3 = v2a - v3a;
        f32x4 t4 = v4a + v5a, t5 = v4a - v5a;
        f32x4 t6 = v6a + v7a, t7 = v6a - v7a;
        f32x4 u0 = t0 + t2, u2 = t0 - t2;
        f32x4 u1 = t1 + t3, u3 = t1 - t3;
        f32x4 u4 = t4 + t6, u6 = t4 - t6;
        f32x4 u5 = t5 + t7, u7 = t5 - t7;
        out[idx]                 = (u0 + u4) * s;
        out[idx + D3]            = (u1 + u5) * s;
        out[idx + D7]            = (u2 + u6) * s;
        out[idx + D7 + D3]       = (u3 + u7) * s;
        out[idx + D12]           = (u0 - u4) * s;
        out[idx + D12 + D3]      = (u1 - u5) * s;
        out[idx + D12 + D7]      = (u2 - u6) * s;
        out[idx + D12 + D7 + D3] = (u3 - u7) * s;
    }
    // ---- column half b ----
    {
        f32x4 t0 = v0b + v1b, t1 = v0b - v1b;
        f32x4 t2 = v2b + v3b, t3 = v2b - v3b;
        f32x4 t4 = v4b + v5b, t5 = v4b - v5b;
        f32x4 t6 = v6b + v7b, t7 = v6b - v7b;
        f32x4 u0 = t0 + t2, u2 = t0 - t2;
        f32x4 u1 = t1 + t3, u3 = t1 - t3;
        f32x4 u4 = t4 + t6, u6 = t4 - t6;
        f32x4 u5 = t5 + t7, u7 = t5 - t7;
        out[idx + HCOLS]                 = (u0 + u4) * s;
        out[idx + D3 + HCOLS]            = (u1 + u5) * s;
        out[idx + D7 + HCOLS]            = (u2 + u6) * s;
        out[idx + D7 + D3 + HCOLS]       = (u3 + u7) * s;
        out[idx + D12 + HCOLS]           = (u0 - u4) * s;
        out[idx + D12 + D3 + HCOLS]      = (u1 - u5) * s;
        out[idx + D12 + D7 + HCOLS]      = (u2 - u6) * s;
        out[idx + D12 + D7 + D3 + HCOLS] = (u3 - u7) * s;
    }
}

extern "C" void kernel_launch(void* const* d_in, const int* in_sizes, int n_in,
                              void* d_out, int out_size, void* d_ws, size_t ws_size,
                              hipStream_t stream) {
    const float* xr = (const float*)d_in[0];
    const float* xi = (const float*)d_in[1];
    float* out = (float*)d_out;

    const int N = NROWS * NCOLS;               // 16,777,216 elements per part
    const int threads = 256;
    const int total   = NBASE * HCOLS;         // 262,144 threads
    const int blocks  = total / threads;       // 1024

    had3_kernel<<<blocks, threads, 0, stream>>>((const f32x4*)xr, (f32x4*)out);

    // Defensive: if the harness wants both parts (concatenated flat),
    // transform the imaginary part into the second half.
    if (out_size >= 2 * N) {
        had3_kernel<<<blocks, threads, 0, stream>>>((const f32x4*)xi,
                                                    (f32x4*)(out + N));
    }
}